// Round 11
// baseline (480.616 us; speedup 1.0000x reference)
//
#include <hip/hip_runtime.h>
#include <hip/hip_bf16.h>

#define HH 192
#define WW 192
#define HWPROD (192*192)
#define EPSBN 1e-5f
#define NSTRIP 2304
#define PADW 194
#define PADSZ (194*194)

typedef _Float16 f16x8 __attribute__((ext_vector_type(8)));
typedef _Float16 f16x4 __attribute__((ext_vector_type(4)));
typedef _Float16 f16x2 __attribute__((ext_vector_type(2)));
typedef float f32x4 __attribute__((ext_vector_type(4)));
typedef float f32x16 __attribute__((ext_vector_type(16)));

// ---------------------------------------------------------------------------
// prep_conv0 R20 (unchanged in R21):
//  blocks [0,1152):    conv0 -> x1T[b][cpair(32)][194][194] f16x2 (padded,
//                      transposed), coalesced 128B-run stores.
//  blocks [1152,1795): whF (proven mapping) + lbf + x1T border zeroing.
// ---------------------------------------------------------------------------
__global__ __launch_bounds__(256) void prep_conv0_k(
                       const float* __restrict__ w0, const float* __restrict__ b0,
                       const float* __restrict__ g0, const float* __restrict__ beta0,
                       const float* __restrict__ m0, const float* __restrict__ v0,
                       const float* __restrict__ lw, const float* __restrict__ lb,
                       const float* __restrict__ lg, const float* __restrict__ lbeta,
                       const float* __restrict__ lm, const float* __restrict__ lv,
                       const float* __restrict__ x,
                       unsigned* __restrict__ x1Tu,
                       _Float16* __restrict__ whF,
                       float* __restrict__ lbf)
{
    const int tid = threadIdx.x;

    if (blockIdx.x >= 1152) {
        // ---------------- prep + border blocks ----------------
        int idx = (blockIdx.x - 1152) * 256 + tid;
        if (idx < 65536) {
            int j    = idx & 7;
            int lane = (idx >> 3) & 63;
            int kg   = (idx >> 9) & 63;   // kg16: 0..63 (K groups of 16)
            int nt   = idx >> 15;         // 0..1 (n-tile of 32)
            int k = kg * 16 + ((lane >> 5) & 1) * 8 + j;
            int n = nt * 32 + (lane & 31);
            float s = lg[n] * rsqrtf(lv[n] + EPSBN);
            whF[idx] = (_Float16)(lw[n * 1024 + k] * s);
        } else if (idx < 65600) {
            int j = idx - 65536;
            float s = lg[j] * rsqrtf(lv[j] + EPSBN);
            lbf[j] = (lb[j] - lm[j]) * s + lbeta[j];
        } else {
            int t = idx - 65600;
            if (t < 98816) {              // x1T border zeroing: 772 dwords/(b,cp)
                int bcp = t / 772;
                int r   = t - bcp * 772;
                int off;
                if (r < 194)      off = r;                         // row 0
                else if (r < 388) off = 193 * 194 + (r - 194);     // row 193
                else if (r < 580) off = (r - 387) * 194;           // col 0, rows 1..192
                else              off = (r - 579) * 194 + 193;     // col 193
                x1Tu[(size_t)bcp * PADSZ + off] = 0u;
            }
        }
        return;
    }

    // ---------------- conv0 blocks ----------------
    __shared__ float wSt[16][64];   // [cin][cout], BN-folded locally
    __shared__ float bS[64];
    for (int t = tid; t < 1024; t += 256) {
        int o = t >> 4, ci = t & 15;
        float s = g0[o] * rsqrtf(v0[o] + EPSBN);
        wSt[ci][o] = w0[t] * s;
    }
    if (tid < 64) {
        float s = g0[tid] * rsqrtf(v0[tid] + EPSBN);
        bS[tid] = (b0[tid] - m0[tid]) * s + beta0[tid];
    }
    __syncthreads();

    // block owns 128 pixels; never straddles a batch (HWPROD%128==0)
    const int pixb = blockIdx.x * 128;
    const int b  = pixb / HWPROD;
    const int pb = pixb - b * HWPROD;
    const int p4  = tid & 31;      // pixel slot (lanes consecutive)
    const int oct = tid >> 5;      // co-octet 0..7

    float xv[4][16];
#pragma unroll
    for (int q = 0; q < 4; q++) {
        const int p = pb + q * 32 + p4;
#pragma unroll
        for (int cin = 0; cin < 16; cin++)
            xv[q][cin] = x[((size_t)b * 16 + cin) * HWPROD + p];
    }

    const f32x4* wSt4 = reinterpret_cast<const f32x4*>(wSt);   // [16][16] quads
    const f32x4* bS4  = reinterpret_cast<const f32x4*>(bS);

    f32x4 acc[4][2];
    {
        f32x4 ba = bS4[oct * 2], bb = bS4[oct * 2 + 1];
#pragma unroll
        for (int q = 0; q < 4; q++) { acc[q][0] = ba; acc[q][1] = bb; }
    }
#pragma unroll
    for (int cin = 0; cin < 16; cin++) {
        const f32x4 wa = wSt4[cin * 16 + oct * 2];
        const f32x4 wb = wSt4[cin * 16 + oct * 2 + 1];
#pragma unroll
        for (int q = 0; q < 4; q++) {
            const float xc = xv[q][cin];
            const f32x4 xb = { xc, xc, xc, xc };
            acc[q][0] = __builtin_elementwise_fma(xb, wa, acc[q][0]);
            acc[q][1] = __builtin_elementwise_fma(xb, wb, acc[q][1]);
        }
    }
#pragma unroll
    for (int q = 0; q < 4; q++) {
        const int p  = pb + q * 32 + p4;
        const int hh = p / WW;
        const int wwp = p - hh * WW;
        union { f32x4 v[2]; float f[8]; } A;
        A.v[0] = acc[q][0]; A.v[1] = acc[q][1];
#pragma unroll
        for (int d = 0; d < 4; d++) {
            f16x2 hv = { (_Float16)fmaxf(A.f[2 * d], 0.f),
                         (_Float16)fmaxf(A.f[2 * d + 1], 0.f) };
            x1Tu[(size_t)(b * 32 + oct * 4 + d) * PADSZ + (hh + 1) * PADW + wwp + 1]
                = *(unsigned*)&hv;
        }
    }
}

// ---------------------------------------------------------------------------
// wn_k R21: identical math to R20, but register-sane.
//  R20 failure: full unroll of the 9-tap loop hoisted 27 loads + all
//  intermediates -> VGPR_Count=256 -> 8% occupancy -> 113 us.
//  Fix: __launch_bounds__(256,4) (<=128-reg budget) + #pragma unroll 1 on
//  the tap loop (per-tap live state ~60 regs). Math order per tap untouched
//  -> bit-identical gzW.
// ---------------------------------------------------------------------------
__global__ __launch_bounds__(256, 4) void wn_k(
                       const float* __restrict__ wnw0, const float* __restrict__ wnb0,
                       const float* __restrict__ wng0, const float* __restrict__ wnbe0,
                       const float* __restrict__ wnm0, const float* __restrict__ wnv0,
                       const float* __restrict__ wnw1, const float* __restrict__ wnb1,
                       const float* __restrict__ wng1, const float* __restrict__ wnbe1,
                       const float* __restrict__ wnm1, const float* __restrict__ wnv1,
                       const float* __restrict__ wnw2, const float* __restrict__ wnb2,
                       const float* __restrict__ wng2, const float* __restrict__ wnbe2,
                       const float* __restrict__ wnm2, const float* __restrict__ wnv2,
                       const float* __restrict__ gxyz,
                       unsigned* __restrict__ gzW)
{
    const int tid = threadIdx.x;
    __shared__ float wp[248];
    for (int t = tid; t < 248; t += 256) {
        float v;
        if (t < 24)       { int o = t / 3;           float s = wng0[o] * rsqrtf(wnv0[o] + EPSBN); v = wnw0[t] * s; }
        else if (t < 32)  { int o = t - 24;          float s = wng0[o] * rsqrtf(wnv0[o] + EPSBN); v = (wnb0[o] - wnm0[o]) * s + wnbe0[o]; }
        else if (t < 96)  { int t2 = t - 32;  int o = t2 >> 3; float s = wng1[o] * rsqrtf(wnv1[o] + EPSBN); v = wnw1[t2] * s; }
        else if (t < 104) { int o = t - 96;          float s = wng1[o] * rsqrtf(wnv1[o] + EPSBN); v = (wnb1[o] - wnm1[o]) * s + wnbe1[o]; }
        else if (t < 232) { int t2 = t - 104; int o = t2 >> 3; float s = wng2[o] * rsqrtf(wnv2[o] + EPSBN); v = wnw2[t2] * s; }
        else              { int o = t - 232;         float s = wng2[o] * rsqrtf(wnv2[o] + EPSBN); v = (wnb2[o] - wnm2[o]) * s + wnbe2[o]; }
        wp[t] = v;
    }
    __syncthreads();

    const int s   = blockIdx.x * 4 + (tid >> 6);   // strip id
    const int t64 = tid & 63;
    const int w   = t64 >> 5;
    const int p31 = t64 & 31;
    const int b   = s / (96 * 6);
    const int rem = s % (96 * 6);
    const int hb  = rem / 6;
    const int c6  = rem % 6;
    const int row = hb * 2 + w;
    const int col = c6 * 32 + p31;

#pragma unroll 1
    for (int tap = 0; tap < 9; tap++) {
        size_t base = ((size_t)(b * 3) * 9 + tap) * HWPROD + (size_t)row * WW + col;
        float z0 = gxyz[base];
        float z1 = gxyz[base + (size_t)9 * HWPROD];
        float z2 = gxyz[base + (size_t)18 * HWPROD];
        float h0[8], h1[8];
#pragma unroll
        for (int o = 0; o < 8; o++) {
            float a = wp[24 + o] + wp[o * 3 + 0] * z0 + wp[o * 3 + 1] * z1 + wp[o * 3 + 2] * z2;
            h0[o] = fmaxf(a, 0.f);
        }
#pragma unroll
        for (int o = 0; o < 8; o++) {
            float a = wp[96 + o];
#pragma unroll
            for (int c = 0; c < 8; c++) a += wp[32 + o * 8 + c] * h0[c];
            h1[o] = fmaxf(a, 0.f);
        }
        float g[16];
#pragma unroll
        for (int o = 0; o < 16; o++) {
            float a = wp[232 + o];
#pragma unroll
            for (int c = 0; c < 8; c++) a += wp[104 + o * 8 + c] * h1[c];
            g[o] = fmaxf(a, 0.f);
        }
        unsigned* dst = gzW + (size_t)(s * 36 + tap * 4) * 128;
#pragma unroll
        for (int d = 0; d < 4; d++) {
            f16x2 lo = { (_Float16)g[2 * d],     (_Float16)g[2 * d + 1] };
            f16x2 hi = { (_Float16)g[8 + 2 * d], (_Float16)g[8 + 2 * d + 1] };
            dst[d * 128 + w * 64 + p31]      = *(unsigned*)&lo;   // oh=0
            dst[d * 128 + w * 64 + 32 + p31] = *(unsigned*)&hi;   // oh=1
        }
    }
}

// ---------------------------------------------------------------------------
// main fused kernel R20 (unchanged in R21): lean strip body.
//  - gq2: 36 coalesced b32 loads from gzW (proven indexing).
//  - xq: direct global loads from padded/transposed x1T (imm offsets,
//    coalesced, block halo ~17 KB L1/L2-resident). No staging, ONE barrier.
// ---------------------------------------------------------------------------
__global__ __launch_bounds__(128, 2) void pconv_main_k(const unsigned* __restrict__ gzW,
                                                       const unsigned* __restrict__ x1Tu,
                                                       const _Float16* __restrict__ whF,
                                                       const float* __restrict__ lbf,
                                                       float* __restrict__ out)
{
    __shared__ __align__(16) float Cb[64 * 67];   // 17,152 B

    const int tid = threadIdx.x;
    const int bid = blockIdx.x;
    // grid: b(4) x hb(96) x c6(6)
    const int b   = bid / (96 * 6);
    const int rem = bid % (96 * 6);
    const int hb  = rem / 6;
    const int c6  = rem % 6;
    const int h   = hb * 2;
    const int wc0 = c6 * 32;

    const int lane = tid & 63;
    const int w    = tid >> 6;        // wave = row strip (h+w)
    const int p31  = lane & 31;       // pixel col within strip
    const int oh   = lane >> 5;       // o-half / k-octet

    // ---- gq2: 36 coalesced b32 loads ----
    f16x2 gq2[9][4];
    {
        const unsigned* gp = gzW + (size_t)bid * 36 * 128 + tid;
#pragma unroll
        for (int t = 0; t < 9; t++)
#pragma unroll
            for (int d = 0; d < 4; d++) {
                unsigned u = gp[(t * 4 + d) * 128];
                gq2[t][d] = *(f16x2*)&u;
            }
    }

    // ---- main loop: 32 channel-pair chunks, direct x1T reads, no barriers --
    const f16x8* whF8 = (const f16x8*)whF;
    // padded base: row (h+w-1)+1 = h+w, col (wc0+p31-1)+1 = wc0+p31
    const unsigned* xb = x1Tu + (size_t)(b * 32) * PADSZ + (h + w) * PADW + (wc0 + p31);

    f32x16 facc0, facc1;
#pragma unroll
    for (int r = 0; r < 16; r++) { facc0[r] = 0.f; facc1[r] = 0.f; }

#pragma unroll 2
    for (int cb = 0; cb < 32; cb++) {
        const int c0 = 2 * cb, c1 = 2 * cb + 1;
        const f16x8 wh00 = whF8[(0 * 64 + c0) * 64 + lane];
        const f16x8 wh01 = whF8[(1 * 64 + c0) * 64 + lane];
        const f16x8 wh10 = whF8[(0 * 64 + c1) * 64 + lane];
        const f16x8 wh11 = whF8[(1 * 64 + c1) * 64 + lane];

        union { f16x2 h2[4]; f16x8 v; } av0, av1;
#pragma unroll
        for (int d = 0; d < 4; d++) { av0.h2[d] = f16x2{0, 0}; av1.h2[d] = f16x2{0, 0}; }
        const unsigned* xr = xb + (size_t)cb * PADSZ;
#pragma unroll
        for (int ky = 0; ky < 3; ky++) {
#pragma unroll
            for (int kx = 0; kx < 3; kx++) {
                const int t = ky * 3 + kx;
                f16x2 xq;
                { unsigned tmp = xr[ky * PADW + kx]; xq = *(f16x2*)&tmp; }
#pragma unroll
                for (int d = 0; d < 4; d++) {
                    // av0 += broadcast(xq.lo) * gq2   (even channel = lo half)
                    asm("v_pk_fma_f16 %0, %1, %2, %0 op_sel:[0,0,0] op_sel_hi:[0,1,1]"
                        : "+v"(av0.h2[d]) : "v"(xq), "v"(gq2[t][d]));
                    // av1 += broadcast(xq.hi) * gq2   (odd channel = hi half)
                    asm("v_pk_fma_f16 %0, %1, %2, %0 op_sel:[1,0,0] op_sel_hi:[1,1,1]"
                        : "+v"(av1.h2[d]) : "v"(xq), "v"(gq2[t][d]));
                }
            }
        }
        facc0 = __builtin_amdgcn_mfma_f32_32x32x16_f16(av0.v, wh00, facc0, 0, 0, 0);
        facc1 = __builtin_amdgcn_mfma_f32_32x32x16_f16(av0.v, wh01, facc1, 0, 0, 0);
        facc0 = __builtin_amdgcn_mfma_f32_32x32x16_f16(av1.v, wh10, facc0, 0, 0, 0);
        facc1 = __builtin_amdgcn_mfma_f32_32x32x16_f16(av1.v, wh11, facc1, 0, 0, 0);
    }

    // ---- epilogue: C/D layout col=lane&31 (=n), row m=(r&3)+8*(r>>2)+4*oh --
    {
        const int n0 = p31;
        const float bias0 = lbf[n0];
        const float bias1 = lbf[n0 + 32];
#pragma unroll
        for (int r = 0; r < 16; r++) {
            const int m = (r & 3) + 8 * (r >> 2) + 4 * oh;   // pixel col in strip
            Cb[n0 * 67 + w * 32 + m]        = fmaxf(facc0[r] + bias0, 0.f);
            Cb[(n0 + 32) * 67 + w * 32 + m] = fmaxf(facc1[r] + bias1, 0.f);
        }
    }
    __syncthreads();   // the kernel's only barrier
    {
        const int col = tid & 31;
        const int nq  = tid >> 5;   // 0..3 -> 16 n's each
#pragma unroll
        for (int rr = 0; rr < 2; rr++) {
            size_t ob = ((size_t)b * 64 + nq * 16) * HWPROD + (size_t)(h + rr) * WW + wc0 + col;
#pragma unroll
            for (int i = 0; i < 16; i++)
                out[ob + (size_t)i * HWPROD] = Cb[(nq * 16 + i) * 67 + rr * 32 + col];
        }
    }
}

// ---------------------------------------------------------------------------
extern "C" void kernel_launch(void* const* d_in, const int* in_sizes, int n_in,
                              void* d_out, int out_size, void* d_ws, size_t ws_size,
                              hipStream_t stream) {
    const float* x    = (const float*)d_in[0];
    // d_in[1] = group_mask: unused by the reference
    const float* gxyz = (const float*)d_in[2];

    char* ws = (char*)d_ws;
    unsigned* x1Tu = (unsigned*)ws;                       // 4,817,408 dwords (19.27 MB)
    _Float16* whF = (_Float16*)(ws + 19269632);           // 65,536 halves (128 KB)
    float* lbf = (float*)(whF + 65536);                   // 64
    unsigned* gzW = (unsigned*)(lbf + 64);                // 10,616,832 dwords (42.5 MB)

    prep_conv0_k<<<1795, 256, 0, stream>>>(
        (const float*)d_in[3],  (const float*)d_in[4],  (const float*)d_in[5],
        (const float*)d_in[6],  (const float*)d_in[7],  (const float*)d_in[8],
        (const float*)d_in[27], (const float*)d_in[28], (const float*)d_in[29],
        (const float*)d_in[30], (const float*)d_in[31], (const float*)d_in[32],
        x, x1Tu, whF, lbf);

    wn_k<<<576, 256, 0, stream>>>(
        (const float*)d_in[9],  (const float*)d_in[10], (const float*)d_in[11],
        (const float*)d_in[12], (const float*)d_in[13], (const float*)d_in[14],
        (const float*)d_in[15], (const float*)d_in[16], (const float*)d_in[17],
        (const float*)d_in[18], (const float*)d_in[19], (const float*)d_in[20],
        (const float*)d_in[21], (const float*)d_in[22], (const float*)d_in[23],
        (const float*)d_in[24], (const float*)d_in[25], (const float*)d_in[26],
        gxyz, gzW);

    pconv_main_k<<<4 * 96 * 6, 128, 0, stream>>>(gzW, x1Tu, whF, lbf,
                                                 (float*)d_out);
}

// Round 12
// 255.177 us; speedup vs baseline: 1.8835x; 1.8835x over previous
//
#include <hip/hip_runtime.h>
#include <hip/hip_bf16.h>

#define HH 192
#define WW 192
#define HWPROD (192*192)
#define EPSBN 1e-5f
#define NSTRIP 2304
#define PADW 194
#define PADSZ (194*194)

typedef _Float16 f16x8 __attribute__((ext_vector_type(8)));
typedef _Float16 f16x4 __attribute__((ext_vector_type(4)));
typedef _Float16 f16x2 __attribute__((ext_vector_type(2)));
typedef float f32x4 __attribute__((ext_vector_type(4)));
typedef float f32x16 __attribute__((ext_vector_type(16)));

// ---------------------------------------------------------------------------
// prep_conv0 R22:
//  blocks [0,1152):    conv0 -> x1T[b][cpair(32)][194][194] f16x2 (padded,
//                      transposed), coalesced 128B-run stores.
//  blocks [1152,1796): whF (proven mapping) + lbf + wnP (BN-folded WeightNet
//                      params, R16-proven expressions) + x1T border zeroing.
// ---------------------------------------------------------------------------
__global__ __launch_bounds__(256) void prep_conv0_k(
                       const float* __restrict__ w0, const float* __restrict__ b0,
                       const float* __restrict__ g0, const float* __restrict__ beta0,
                       const float* __restrict__ m0, const float* __restrict__ v0,
                       const float* __restrict__ wnw0, const float* __restrict__ wnb0,
                       const float* __restrict__ wng0, const float* __restrict__ wnbe0,
                       const float* __restrict__ wnm0, const float* __restrict__ wnv0,
                       const float* __restrict__ wnw1, const float* __restrict__ wnb1,
                       const float* __restrict__ wng1, const float* __restrict__ wnbe1,
                       const float* __restrict__ wnm1, const float* __restrict__ wnv1,
                       const float* __restrict__ wnw2, const float* __restrict__ wnb2,
                       const float* __restrict__ wng2, const float* __restrict__ wnbe2,
                       const float* __restrict__ wnm2, const float* __restrict__ wnv2,
                       const float* __restrict__ lw, const float* __restrict__ lb,
                       const float* __restrict__ lg, const float* __restrict__ lbeta,
                       const float* __restrict__ lm, const float* __restrict__ lv,
                       const float* __restrict__ x,
                       unsigned* __restrict__ x1Tu,
                       _Float16* __restrict__ whF,
                       float* __restrict__ lbf,
                       float* __restrict__ wnP)
{
    const int tid = threadIdx.x;

    if (blockIdx.x >= 1152) {
        // ---------------- prep + border blocks ----------------
        int idx = (blockIdx.x - 1152) * 256 + tid;
        if (idx < 65536) {
            int j    = idx & 7;
            int lane = (idx >> 3) & 63;
            int kg   = (idx >> 9) & 63;   // kg16: 0..63 (K groups of 16)
            int nt   = idx >> 15;         // 0..1 (n-tile of 32)
            int k = kg * 16 + ((lane >> 5) & 1) * 8 + j;
            int n = nt * 32 + (lane & 31);
            float s = lg[n] * rsqrtf(lv[n] + EPSBN);
            whF[idx] = (_Float16)(lw[n * 1024 + k] * s);
        } else if (idx < 65600) {
            int j = idx - 65536;
            float s = lg[j] * rsqrtf(lv[j] + EPSBN);
            lbf[j] = (lb[j] - lm[j]) * s + lbeta[j];
        } else if (idx < 65848) {
            int t = idx - 65600;
            // wnP layout: [0,24) w0n  [24,32) b0n  [32,96) w1n  [96,104) b1n
            //             [104,232) w2n  [232,248) b2n   (all BN-fused)
            if (t < 24)       { int o = t / 3;           float s = wng0[o] * rsqrtf(wnv0[o] + EPSBN); wnP[t] = wnw0[t] * s; }
            else if (t < 32)  { int o = t - 24;          float s = wng0[o] * rsqrtf(wnv0[o] + EPSBN); wnP[t] = (wnb0[o] - wnm0[o]) * s + wnbe0[o]; }
            else if (t < 96)  { int t2 = t - 32;  int o = t2 >> 3; float s = wng1[o] * rsqrtf(wnv1[o] + EPSBN); wnP[t] = wnw1[t2] * s; }
            else if (t < 104) { int o = t - 96;          float s = wng1[o] * rsqrtf(wnv1[o] + EPSBN); wnP[t] = (wnb1[o] - wnm1[o]) * s + wnbe1[o]; }
            else if (t < 232) { int t2 = t - 104; int o = t2 >> 3; float s = wng2[o] * rsqrtf(wnv2[o] + EPSBN); wnP[t] = wnw2[t2] * s; }
            else              { int o = t - 232;         float s = wng2[o] * rsqrtf(wnv2[o] + EPSBN); wnP[t] = (wnb2[o] - wnm2[o]) * s + wnbe2[o]; }
        } else {
            int t = idx - 65848;
            if (t < 98816) {              // x1T border zeroing: 772 dwords/(b,cp)
                int bcp = t / 772;
                int r   = t - bcp * 772;
                int off;
                if (r < 194)      off = r;                         // row 0
                else if (r < 388) off = 193 * 194 + (r - 194);     // row 193
                else if (r < 580) off = (r - 387) * 194;           // col 0, rows 1..192
                else              off = (r - 579) * 194 + 193;     // col 193
                x1Tu[(size_t)bcp * PADSZ + off] = 0u;
            }
        }
        return;
    }

    // ---------------- conv0 blocks ----------------
    __shared__ float wSt[16][64];   // [cin][cout], BN-folded locally
    __shared__ float bS[64];
    for (int t = tid; t < 1024; t += 256) {
        int o = t >> 4, ci = t & 15;
        float s = g0[o] * rsqrtf(v0[o] + EPSBN);
        wSt[ci][o] = w0[t] * s;
    }
    if (tid < 64) {
        float s = g0[tid] * rsqrtf(v0[tid] + EPSBN);
        bS[tid] = (b0[tid] - m0[tid]) * s + beta0[tid];
    }
    __syncthreads();

    // block owns 128 pixels; never straddles a batch (HWPROD%128==0)
    const int pixb = blockIdx.x * 128;
    const int b  = pixb / HWPROD;
    const int pb = pixb - b * HWPROD;
    const int p4  = tid & 31;      // pixel slot (lanes consecutive)
    const int oct = tid >> 5;      // co-octet 0..7

    float xv[4][16];
#pragma unroll
    for (int q = 0; q < 4; q++) {
        const int p = pb + q * 32 + p4;
#pragma unroll
        for (int cin = 0; cin < 16; cin++)
            xv[q][cin] = x[((size_t)b * 16 + cin) * HWPROD + p];
    }

    const f32x4* wSt4 = reinterpret_cast<const f32x4*>(wSt);   // [16][16] quads
    const f32x4* bS4  = reinterpret_cast<const f32x4*>(bS);

    f32x4 acc[4][2];
    {
        f32x4 ba = bS4[oct * 2], bb = bS4[oct * 2 + 1];
#pragma unroll
        for (int q = 0; q < 4; q++) { acc[q][0] = ba; acc[q][1] = bb; }
    }
#pragma unroll
    for (int cin = 0; cin < 16; cin++) {
        const f32x4 wa = wSt4[cin * 16 + oct * 2];
        const f32x4 wb = wSt4[cin * 16 + oct * 2 + 1];
#pragma unroll
        for (int q = 0; q < 4; q++) {
            const float xc = xv[q][cin];
            const f32x4 xb = { xc, xc, xc, xc };
            acc[q][0] = __builtin_elementwise_fma(xb, wa, acc[q][0]);
            acc[q][1] = __builtin_elementwise_fma(xb, wb, acc[q][1]);
        }
    }
#pragma unroll
    for (int q = 0; q < 4; q++) {
        const int p  = pb + q * 32 + p4;
        const int hh = p / WW;
        const int wwp = p - hh * WW;
        union { f32x4 v[2]; float f[8]; } A;
        A.v[0] = acc[q][0]; A.v[1] = acc[q][1];
#pragma unroll
        for (int d = 0; d < 4; d++) {
            f16x2 hv = { (_Float16)fmaxf(A.f[2 * d], 0.f),
                         (_Float16)fmaxf(A.f[2 * d + 1], 0.f) };
            x1Tu[(size_t)(b * 32 + oct * 4 + d) * PADSZ + (hh + 1) * PADW + wwp + 1]
                = *(unsigned*)&hv;
        }
    }
}

// ---------------------------------------------------------------------------
// wn_k R22: weights as SGPRs.
//  R20 failure: weights in LDS -> every FMA pays ds_read latency, 9 waves/CU
//  can't hide it -> 113 us. R21 failure: (256,4) cap forced scratch spills
//  (FETCH 17.8->570 MB) -> 257 us. Fix: read BN-folded weights from global
//  wnP with UNIFORM indices -> compiler emits s_load -> SGPR operands (free
//  on VALU). No LDS, no reg cap, unroll 1 (per-tap live state ~50 VGPR).
//  gxyz loads + gzW write layout unchanged (proven). Numerics identical
//  (same folded values, same expression order).
// ---------------------------------------------------------------------------
__global__ __launch_bounds__(256) void wn_k(const float* __restrict__ wnP,
                                            const float* __restrict__ gxyz,
                                            unsigned* __restrict__ gzW)
{
    const int tid = threadIdx.x;
    const int s   = blockIdx.x * 4 + (tid >> 6);   // strip id
    const int t64 = tid & 63;
    const int w   = t64 >> 5;
    const int p31 = t64 & 31;
    const int b   = s / (96 * 6);
    const int rem = s % (96 * 6);
    const int hb  = rem / 6;
    const int c6  = rem % 6;
    const int row = hb * 2 + w;
    const int col = c6 * 32 + p31;

#pragma unroll 1
    for (int tap = 0; tap < 9; tap++) {
        size_t base = ((size_t)(b * 3) * 9 + tap) * HWPROD + (size_t)row * WW + col;
        float z0 = gxyz[base];
        float z1 = gxyz[base + (size_t)9 * HWPROD];
        float z2 = gxyz[base + (size_t)18 * HWPROD];
        float h0[8], h1[8];
#pragma unroll
        for (int o = 0; o < 8; o++) {
            float a = wnP[24 + o] + wnP[o * 3 + 0] * z0 + wnP[o * 3 + 1] * z1 + wnP[o * 3 + 2] * z2;
            h0[o] = fmaxf(a, 0.f);
        }
#pragma unroll
        for (int o = 0; o < 8; o++) {
            float a = wnP[96 + o];
#pragma unroll
            for (int c = 0; c < 8; c++) a += wnP[32 + o * 8 + c] * h0[c];
            h1[o] = fmaxf(a, 0.f);
        }
        float g[16];
#pragma unroll
        for (int o = 0; o < 16; o++) {
            float a = wnP[232 + o];
#pragma unroll
            for (int c = 0; c < 8; c++) a += wnP[104 + o * 8 + c] * h1[c];
            g[o] = fmaxf(a, 0.f);
        }
        unsigned* dst = gzW + (size_t)(s * 36 + tap * 4) * 128;
#pragma unroll
        for (int d = 0; d < 4; d++) {
            f16x2 lo = { (_Float16)g[2 * d],     (_Float16)g[2 * d + 1] };
            f16x2 hi = { (_Float16)g[8 + 2 * d], (_Float16)g[8 + 2 * d + 1] };
            dst[d * 128 + w * 64 + p31]      = *(unsigned*)&lo;   // oh=0
            dst[d * 128 + w * 64 + 32 + p31] = *(unsigned*)&hi;   // oh=1
        }
    }
}

// ---------------------------------------------------------------------------
// main fused kernel R20 (unchanged): lean strip body.
//  - gq2: 36 coalesced b32 loads from gzW (proven indexing).
//  - xq: direct global loads from padded/transposed x1T (imm offsets,
//    coalesced, block halo ~17 KB L1/L2-resident). No staging, ONE barrier.
// ---------------------------------------------------------------------------
__global__ __launch_bounds__(128, 2) void pconv_main_k(const unsigned* __restrict__ gzW,
                                                       const unsigned* __restrict__ x1Tu,
                                                       const _Float16* __restrict__ whF,
                                                       const float* __restrict__ lbf,
                                                       float* __restrict__ out)
{
    __shared__ __align__(16) float Cb[64 * 67];   // 17,152 B

    const int tid = threadIdx.x;
    const int bid = blockIdx.x;
    // grid: b(4) x hb(96) x c6(6)
    const int b   = bid / (96 * 6);
    const int rem = bid % (96 * 6);
    const int hb  = rem / 6;
    const int c6  = rem % 6;
    const int h   = hb * 2;
    const int wc0 = c6 * 32;

    const int lane = tid & 63;
    const int w    = tid >> 6;        // wave = row strip (h+w)
    const int p31  = lane & 31;       // pixel col within strip
    const int oh   = lane >> 5;       // o-half / k-octet

    // ---- gq2: 36 coalesced b32 loads ----
    f16x2 gq2[9][4];
    {
        const unsigned* gp = gzW + (size_t)bid * 36 * 128 + tid;
#pragma unroll
        for (int t = 0; t < 9; t++)
#pragma unroll
            for (int d = 0; d < 4; d++) {
                unsigned u = gp[(t * 4 + d) * 128];
                gq2[t][d] = *(f16x2*)&u;
            }
    }

    // ---- main loop: 32 channel-pair chunks, direct x1T reads, no barriers --
    const f16x8* whF8 = (const f16x8*)whF;
    // padded base: row (h+w-1)+1 = h+w, col (wc0+p31-1)+1 = wc0+p31
    const unsigned* xb = x1Tu + (size_t)(b * 32) * PADSZ + (h + w) * PADW + (wc0 + p31);

    f32x16 facc0, facc1;
#pragma unroll
    for (int r = 0; r < 16; r++) { facc0[r] = 0.f; facc1[r] = 0.f; }

#pragma unroll 2
    for (int cb = 0; cb < 32; cb++) {
        const int c0 = 2 * cb, c1 = 2 * cb + 1;
        const f16x8 wh00 = whF8[(0 * 64 + c0) * 64 + lane];
        const f16x8 wh01 = whF8[(1 * 64 + c0) * 64 + lane];
        const f16x8 wh10 = whF8[(0 * 64 + c1) * 64 + lane];
        const f16x8 wh11 = whF8[(1 * 64 + c1) * 64 + lane];

        union { f16x2 h2[4]; f16x8 v; } av0, av1;
#pragma unroll
        for (int d = 0; d < 4; d++) { av0.h2[d] = f16x2{0, 0}; av1.h2[d] = f16x2{0, 0}; }
        const unsigned* xr = xb + (size_t)cb * PADSZ;
#pragma unroll
        for (int ky = 0; ky < 3; ky++) {
#pragma unroll
            for (int kx = 0; kx < 3; kx++) {
                const int t = ky * 3 + kx;
                f16x2 xq;
                { unsigned tmp = xr[ky * PADW + kx]; xq = *(f16x2*)&tmp; }
#pragma unroll
                for (int d = 0; d < 4; d++) {
                    // av0 += broadcast(xq.lo) * gq2   (even channel = lo half)
                    asm("v_pk_fma_f16 %0, %1, %2, %0 op_sel:[0,0,0] op_sel_hi:[0,1,1]"
                        : "+v"(av0.h2[d]) : "v"(xq), "v"(gq2[t][d]));
                    // av1 += broadcast(xq.hi) * gq2   (odd channel = hi half)
                    asm("v_pk_fma_f16 %0, %1, %2, %0 op_sel:[1,0,0] op_sel_hi:[1,1,1]"
                        : "+v"(av1.h2[d]) : "v"(xq), "v"(gq2[t][d]));
                }
            }
        }
        facc0 = __builtin_amdgcn_mfma_f32_32x32x16_f16(av0.v, wh00, facc0, 0, 0, 0);
        facc1 = __builtin_amdgcn_mfma_f32_32x32x16_f16(av0.v, wh01, facc1, 0, 0, 0);
        facc0 = __builtin_amdgcn_mfma_f32_32x32x16_f16(av1.v, wh10, facc0, 0, 0, 0);
        facc1 = __builtin_amdgcn_mfma_f32_32x32x16_f16(av1.v, wh11, facc1, 0, 0, 0);
    }

    // ---- epilogue: C/D layout col=lane&31 (=n), row m=(r&3)+8*(r>>2)+4*oh --
    {
        const int n0 = p31;
        const float bias0 = lbf[n0];
        const float bias1 = lbf[n0 + 32];
#pragma unroll
        for (int r = 0; r < 16; r++) {
            const int m = (r & 3) + 8 * (r >> 2) + 4 * oh;   // pixel col in strip
            Cb[n0 * 67 + w * 32 + m]        = fmaxf(facc0[r] + bias0, 0.f);
            Cb[(n0 + 32) * 67 + w * 32 + m] = fmaxf(facc1[r] + bias1, 0.f);
        }
    }
    __syncthreads();   // the kernel's only barrier
    {
        const int col = tid & 31;
        const int nq  = tid >> 5;   // 0..3 -> 16 n's each
#pragma unroll
        for (int rr = 0; rr < 2; rr++) {
            size_t ob = ((size_t)b * 64 + nq * 16) * HWPROD + (size_t)(h + rr) * WW + wc0 + col;
#pragma unroll
            for (int i = 0; i < 16; i++)
                out[ob + (size_t)i * HWPROD] = Cb[(nq * 16 + i) * 67 + rr * 32 + col];
        }
    }
}

// ---------------------------------------------------------------------------
extern "C" void kernel_launch(void* const* d_in, const int* in_sizes, int n_in,
                              void* d_out, int out_size, void* d_ws, size_t ws_size,
                              hipStream_t stream) {
    const float* x    = (const float*)d_in[0];
    // d_in[1] = group_mask: unused by the reference
    const float* gxyz = (const float*)d_in[2];

    char* ws = (char*)d_ws;
    unsigned* x1Tu = (unsigned*)ws;                       // 4,817,408 dwords (19.27 MB)
    _Float16* whF = (_Float16*)(ws + 19269632);           // 65,536 halves (128 KB)
    float* lbf = (float*)(whF + 65536);                   // 64
    float* wnP = lbf + 64;                                // 248
    unsigned* gzW = (unsigned*)(wnP + 248);               // 10,616,832 dwords (42.5 MB)

    prep_conv0_k<<<1796, 256, 0, stream>>>(
        (const float*)d_in[3],  (const float*)d_in[4],  (const float*)d_in[5],
        (const float*)d_in[6],  (const float*)d_in[7],  (const float*)d_in[8],
        (const float*)d_in[9],  (const float*)d_in[10], (const float*)d_in[11],
        (const float*)d_in[12], (const float*)d_in[13], (const float*)d_in[14],
        (const float*)d_in[15], (const float*)d_in[16], (const float*)d_in[17],
        (const float*)d_in[18], (const float*)d_in[19], (const float*)d_in[20],
        (const float*)d_in[21], (const float*)d_in[22], (const float*)d_in[23],
        (const float*)d_in[24], (const float*)d_in[25], (const float*)d_in[26],
        (const float*)d_in[27], (const float*)d_in[28], (const float*)d_in[29],
        (const float*)d_in[30], (const float*)d_in[31], (const float*)d_in[32],
        x, x1Tu, whF, lbf, wnP);

    wn_k<<<576, 256, 0, stream>>>(wnP, gxyz, gzW);

    pconv_main_k<<<4 * 96 * 6, 128, 0, stream>>>(gzW, x1Tu, whF, lbf,
                                                 (float*)d_out);
}

// Round 13
// 205.687 us; speedup vs baseline: 2.3366x; 1.2406x over previous
//
#include <hip/hip_runtime.h>
#include <hip/hip_bf16.h>

#define HH 192
#define WW 192
#define HWPROD (192*192)
#define EPSBN 1e-5f

typedef _Float16 f16x8 __attribute__((ext_vector_type(8)));
typedef _Float16 f16x4 __attribute__((ext_vector_type(4)));
typedef _Float16 f16x2 __attribute__((ext_vector_type(2)));
typedef float f32x4 __attribute__((ext_vector_type(4)));
typedef float f32x16 __attribute__((ext_vector_type(16)));

// ---------------------------------------------------------------------------
// prep_conv0 (R16 version -- best verified):
//  blocks [0,1152):    conv0, coalesced f16x8 stores; x1 pixel-major [B,H,W,64].
//  blocks [1152,1414): whF/lbf/wnP prep (proven mapping).
// ---------------------------------------------------------------------------
__global__ __launch_bounds__(256) void prep_conv0_k(
                       const float* __restrict__ w0, const float* __restrict__ b0,
                       const float* __restrict__ g0, const float* __restrict__ beta0,
                       const float* __restrict__ m0, const float* __restrict__ v0,
                       const float* __restrict__ wnw0, const float* __restrict__ wnb0,
                       const float* __restrict__ wng0, const float* __restrict__ wnbe0,
                       const float* __restrict__ wnm0, const float* __restrict__ wnv0,
                       const float* __restrict__ wnw1, const float* __restrict__ wnb1,
                       const float* __restrict__ wng1, const float* __restrict__ wnbe1,
                       const float* __restrict__ wnm1, const float* __restrict__ wnv1,
                       const float* __restrict__ wnw2, const float* __restrict__ wnb2,
                       const float* __restrict__ wng2, const float* __restrict__ wnbe2,
                       const float* __restrict__ wnm2, const float* __restrict__ wnv2,
                       const float* __restrict__ lw, const float* __restrict__ lb,
                       const float* __restrict__ lg, const float* __restrict__ lbeta,
                       const float* __restrict__ lm, const float* __restrict__ lv,
                       const float* __restrict__ x,
                       _Float16* __restrict__ x1L,
                       _Float16* __restrict__ whF,
                       float* __restrict__ lbf,
                       float* __restrict__ wnP)
{
    const int tid = threadIdx.x;

    if (blockIdx.x >= 1152) {
        // ---------------- prep blocks ----------------
        int idx = (blockIdx.x - 1152) * 256 + tid;
        if (idx < 65536) {
            int j    = idx & 7;
            int lane = (idx >> 3) & 63;
            int kg   = (idx >> 9) & 63;   // kg16: 0..63 (K groups of 16)
            int nt   = idx >> 15;         // 0..1 (n-tile of 32)
            int k = kg * 16 + ((lane >> 5) & 1) * 8 + j;
            int n = nt * 32 + (lane & 31);
            float s = lg[n] * rsqrtf(lv[n] + EPSBN);
            whF[idx] = (_Float16)(lw[n * 1024 + k] * s);
        } else if (idx < 65600) {
            int j = idx - 65536;
            float s = lg[j] * rsqrtf(lv[j] + EPSBN);
            lbf[j] = (lb[j] - lm[j]) * s + lbeta[j];
        } else if (idx < 65848) {
            int t = idx - 65600;
            // wnP layout: [0,24) w0n  [24,32) b0n  [32,96) w1n  [96,104) b1n
            //             [104,232) w2n  [232,248) b2n   (all BN-fused)
            if (t < 24)       { int o = t / 3;           float s = wng0[o] * rsqrtf(wnv0[o] + EPSBN); wnP[t] = wnw0[t] * s; }
            else if (t < 32)  { int o = t - 24;          float s = wng0[o] * rsqrtf(wnv0[o] + EPSBN); wnP[t] = (wnb0[o] - wnm0[o]) * s + wnbe0[o]; }
            else if (t < 96)  { int t2 = t - 32;  int o = t2 >> 3; float s = wng1[o] * rsqrtf(wnv1[o] + EPSBN); wnP[t] = wnw1[t2] * s; }
            else if (t < 104) { int o = t - 96;          float s = wng1[o] * rsqrtf(wnv1[o] + EPSBN); wnP[t] = (wnb1[o] - wnm1[o]) * s + wnbe1[o]; }
            else if (t < 232) { int t2 = t - 104; int o = t2 >> 3; float s = wng2[o] * rsqrtf(wnv2[o] + EPSBN); wnP[t] = wnw2[t2] * s; }
            else if (t < 248) { int o = t - 232;         float s = wng2[o] * rsqrtf(wnv2[o] + EPSBN); wnP[t] = (wnb2[o] - wnm2[o]) * s + wnbe2[o]; }
        }
        return;
    }

    // ---------------- conv0 blocks ----------------
    __shared__ float wSt[16][64];   // [cin][cout], BN-folded locally
    __shared__ float bS[64];
    for (int t = tid; t < 1024; t += 256) {
        int o = t >> 4, ci = t & 15;
        float s = g0[o] * rsqrtf(v0[o] + EPSBN);
        wSt[ci][o] = w0[t] * s;
    }
    if (tid < 64) {
        float s = g0[tid] * rsqrtf(v0[tid] + EPSBN);
        bS[tid] = (b0[tid] - m0[tid]) * s + beta0[tid];
    }
    __syncthreads();

    // block owns 128 pixels; 128 never straddles a batch (HWPROD%128==0)
    const int pixb = blockIdx.x * 128;
    const int b  = pixb / HWPROD;
    const int pb = pixb - b * HWPROD;
    const int p4  = tid >> 3;      // pixel slot 0..31
    const int oct = tid & 7;       // co-octet 0..7

    float xv[4][16];
#pragma unroll
    for (int q = 0; q < 4; q++) {
        const int p = pb + q * 32 + p4;
#pragma unroll
        for (int cin = 0; cin < 16; cin++)
            xv[q][cin] = x[((size_t)b * 16 + cin) * HWPROD + p];
    }

    const f32x4* wSt4 = reinterpret_cast<const f32x4*>(wSt);   // [16][16] quads
    const f32x4* bS4  = reinterpret_cast<const f32x4*>(bS);

    f32x4 acc[4][2];
    {
        f32x4 ba = bS4[oct * 2], bb = bS4[oct * 2 + 1];
#pragma unroll
        for (int q = 0; q < 4; q++) { acc[q][0] = ba; acc[q][1] = bb; }
    }
#pragma unroll
    for (int cin = 0; cin < 16; cin++) {
        const f32x4 wa = wSt4[cin * 16 + oct * 2];
        const f32x4 wb = wSt4[cin * 16 + oct * 2 + 1];
#pragma unroll
        for (int q = 0; q < 4; q++) {
            const float xc = xv[q][cin];
            const f32x4 xb = { xc, xc, xc, xc };
            acc[q][0] = __builtin_elementwise_fma(xb, wa, acc[q][0]);
            acc[q][1] = __builtin_elementwise_fma(xb, wb, acc[q][1]);
        }
    }
    const f32x4 z4 = { 0.f, 0.f, 0.f, 0.f };
#pragma unroll
    for (int q = 0; q < 4; q++) {
        union { f16x4 h4[2]; f16x8 v; } O;
        O.h4[0] = __builtin_convertvector(__builtin_elementwise_max(acc[q][0], z4), f16x4);
        O.h4[1] = __builtin_convertvector(__builtin_elementwise_max(acc[q][1], z4), f16x4);
        *(f16x8*)(x1L + (size_t)(pixb + q * 32 + p4) * 64 + oct * 8) = O.v;
    }
}

// ---------------------------------------------------------------------------
// main fused kernel R23 = R16 main (best verified: 80.0 us) + chunked XCD
// swizzle on blockIdx (T1): bid = (raw&7)*288 + (raw>>3), bijective since
// 2304 = 8*288. Row-halo neighbor blocks (bid +- 6) and the shared whF/x1L
// slabs now land on the same XCD's L2 instead of round-robining across 8.
// Everything else byte-identical to R16.
// ---------------------------------------------------------------------------
__global__ __launch_bounds__(128, 2) void pconv_main_k(const float* __restrict__ gxyz,
                                                       const _Float16* __restrict__ x1L,
                                                       const _Float16* __restrict__ whF,
                                                       const float* __restrict__ lbf,
                                                       const float* __restrict__ wnP,
                                                       float* __restrict__ out)
{
    __shared__ __align__(16) char smem[19456];
    unsigned*  xSu = reinterpret_cast<unsigned*>(smem);   // [32 cpair][4r*34c] dwords, stride 137
    _Float16*  gzF = reinterpret_cast<_Float16*>(smem);   // [64 px][152] halves (dead after S2)
    float*     Cb  = reinterpret_cast<float*>(smem);      // [64 n][67] f32 (epilogue)

    const int tid = threadIdx.x;
    const int bid = ((int)(blockIdx.x & 7)) * 288 + ((int)blockIdx.x >> 3);  // XCD swizzle
    // grid: b(4) x hb(96) x c6(6)
    const int b   = bid / (96 * 6);
    const int rem = bid % (96 * 6);
    const int hb  = rem / 6;
    const int c6  = rem % 6;
    const int h   = hb * 2;
    const int wc0 = c6 * 32;

    // ---- WeightNet 3->8->8->16 (BN+ReLU fused): 576 (pixel,tap) units ----
    for (int u = tid; u < 576; u += 128) {
        int col = u & 31, rrow = (u >> 5) & 1, tap = u >> 6;
        size_t base = ((size_t)(b * 3) * 9 + tap) * HWPROD + (size_t)(h + rrow) * WW + wc0 + col;
        float z0 = gxyz[base];
        float z1 = gxyz[base + (size_t)9 * HWPROD];
        float z2 = gxyz[base + (size_t)18 * HWPROD];
        float h0[8], h1[8];
#pragma unroll
        for (int o = 0; o < 8; o++) {
            float a = wnP[24 + o] + wnP[o * 3 + 0] * z0 + wnP[o * 3 + 1] * z1 + wnP[o * 3 + 2] * z2;
            h0[o] = fmaxf(a, 0.f);
        }
#pragma unroll
        for (int o = 0; o < 8; o++) {
            float a = wnP[96 + o];
#pragma unroll
            for (int c = 0; c < 8; c++) a += wnP[32 + o * 8 + c] * h0[c];
            h1[o] = fmaxf(a, 0.f);
        }
        float g[16];
#pragma unroll
        for (int o = 0; o < 16; o++) {
            float a = wnP[232 + o];
#pragma unroll
            for (int c = 0; c < 8; c++) a += wnP[104 + o * 8 + c] * h1[c];
            g[o] = fmaxf(a, 0.f);
        }
        f16x8 lo, hi;
#pragma unroll
        for (int o = 0; o < 8; o++) { lo[o] = (_Float16)g[o]; hi[o] = (_Float16)g[o + 8]; }
        int pixb = u & 63;
        *(f16x8*)&gzF[pixb * 152 + tap * 16]     = lo;
        *(f16x8*)&gzF[pixb * 152 + tap * 16 + 8] = hi;
    }
    __syncthreads();   // S1: gzF visible

    const int lane = tid & 63;
    const int w    = tid >> 6;        // wave = row strip (h+w)
    const int p31  = lane & 31;       // pixel col within strip
    const int oh   = lane >> 5;       // o-half / k-octet
    const int pixb = w * 32 + p31;

    // gz for this lane's (pixel, o-half): 9 taps x 4 f16x2 pairs in registers
    f16x2 gq2[9][4];
#pragma unroll
    for (int t = 0; t < 9; t++) {
        union { f16x8 v; f16x2 h[4]; } G;
        G.v = *(const f16x8*)&gzF[pixb * 152 + t * 16 + oh * 8];
#pragma unroll
        for (int d = 0; d < 4; d++) gq2[t][d] = G.h[d];
    }
    __syncthreads();   // S2: gzF dead; xS region may be written

    // ---- stage x1 halo transposed: xS[cpair][rr*34+cc] f16x2, stride 137 ----
    // interior cols cc=1..32 (always in-range horizontally): 16 exact iters
    for (int i = 0; i < 16; i++) {
        int u  = i * 128 + tid;
        int cq = u & 15;                  // channel quad (4 ch = 2 pairs)
        int cc = ((u >> 4) & 31) + 1;
        int rr = u >> 9;                  // 0..3
        int hr = h + rr - 1;
        uint2 v = {0u, 0u};
        if (hr >= 0 && hr < HH)
            v = *(const uint2*)(x1L + (((size_t)b * HH + hr) * WW + wc0 + cc - 1) * 64 + cq * 4);
        xSu[(2 * cq) * 137 + rr * 34 + cc]     = v.x;
        xSu[(2 * cq + 1) * 137 + rr * 34 + cc] = v.y;
    }
    // halo cols cc in {0,33}: 1 iter (128 units)
    {
        int cq   = tid & 15;
        int side = (tid >> 4) & 1;
        int rr   = tid >> 5;              // 0..3
        int cc   = side ? 33 : 0;
        int hr = h + rr - 1;
        int wc = wc0 + cc - 1;
        uint2 v = {0u, 0u};
        if (hr >= 0 && hr < HH && wc >= 0 && wc < WW)
            v = *(const uint2*)(x1L + (((size_t)b * HH + hr) * WW + wc) * 64 + cq * 4);
        xSu[(2 * cq) * 137 + rr * 34 + cc]     = v.x;
        xSu[(2 * cq + 1) * 137 + rr * 34 + cc] = v.y;
    }
    __syncthreads();   // S3: xS ready -- last barrier before epilogue

    // ---- main loop: 32 channel-pair chunks, zero barriers ----
    const f16x8* whF8 = (const f16x8*)whF;
    const unsigned* xrow = xSu + w * 34 + p31;

    f32x16 facc0, facc1;
#pragma unroll
    for (int r = 0; r < 16; r++) { facc0[r] = 0.f; facc1[r] = 0.f; }

#pragma unroll 2
    for (int cb = 0; cb < 32; cb++) {
        const int c0 = 2 * cb, c1 = 2 * cb + 1;
        // B fragments (whF proven layout): index (nt*64 + c)*64 + lane
        const f16x8 wh00 = whF8[(0 * 64 + c0) * 64 + lane];
        const f16x8 wh01 = whF8[(1 * 64 + c0) * 64 + lane];
        const f16x8 wh10 = whF8[(0 * 64 + c1) * 64 + lane];
        const f16x8 wh11 = whF8[(1 * 64 + c1) * 64 + lane];

        union { f16x2 h2[4]; f16x8 v; } av0, av1;
#pragma unroll
        for (int d = 0; d < 4; d++) { av0.h2[d] = f16x2{0, 0}; av1.h2[d] = f16x2{0, 0}; }
        const unsigned* xr = xrow + cb * 137;
#pragma unroll
        for (int ky = 0; ky < 3; ky++) {
#pragma unroll
            for (int kx = 0; kx < 3; kx++) {
                const int t = ky * 3 + kx;
                f16x2 xq;
                { unsigned tmp = xr[ky * 34 + kx]; xq = *(f16x2*)&tmp; }
#pragma unroll
                for (int d = 0; d < 4; d++) {
                    // av0 += broadcast(xq.lo) * gq2   (channel c0 = even = lo half)
                    asm("v_pk_fma_f16 %0, %1, %2, %0 op_sel:[0,0,0] op_sel_hi:[0,1,1]"
                        : "+v"(av0.h2[d]) : "v"(xq), "v"(gq2[t][d]));
                    // av1 += broadcast(xq.hi) * gq2   (channel c1 = odd = hi half)
                    asm("v_pk_fma_f16 %0, %1, %2, %0 op_sel:[1,0,0] op_sel_hi:[1,1,1]"
                        : "+v"(av1.h2[d]) : "v"(xq), "v"(gq2[t][d]));
                }
            }
        }
        facc0 = __builtin_amdgcn_mfma_f32_32x32x16_f16(av0.v, wh00, facc0, 0, 0, 0);
        facc1 = __builtin_amdgcn_mfma_f32_32x32x16_f16(av0.v, wh01, facc1, 0, 0, 0);
        facc0 = __builtin_amdgcn_mfma_f32_32x32x16_f16(av1.v, wh10, facc0, 0, 0, 0);
        facc1 = __builtin_amdgcn_mfma_f32_32x32x16_f16(av1.v, wh11, facc1, 0, 0, 0);
    }
    __syncthreads();   // S4: xS dead (all waves done with MFMAs)

    // ---- epilogue: C/D layout col=lane&31 (=n), row m=(r&3)+8*(r>>2)+4*oh ----
    {
        const int n0 = p31;
        const float bias0 = lbf[n0];
        const float bias1 = lbf[n0 + 32];
#pragma unroll
        for (int r = 0; r < 16; r++) {
            const int m = (r & 3) + 8 * (r >> 2) + 4 * oh;   // pixel col in strip
            Cb[n0 * 67 + w * 32 + m]        = fmaxf(facc0[r] + bias0, 0.f);
            Cb[(n0 + 32) * 67 + w * 32 + m] = fmaxf(facc1[r] + bias1, 0.f);
        }
    }
    __syncthreads();   // S5
    {
        const int col = tid & 31;
        const int nq  = tid >> 5;   // 0..3 -> 16 n's each
#pragma unroll
        for (int rr = 0; rr < 2; rr++) {
            size_t ob = ((size_t)b * 64 + nq * 16) * HWPROD + (size_t)(h + rr) * WW + wc0 + col;
#pragma unroll
            for (int i = 0; i < 16; i++)
                out[ob + (size_t)i * HWPROD] = Cb[(nq * 16 + i) * 67 + rr * 32 + col];
        }
    }
}

// ---------------------------------------------------------------------------
extern "C" void kernel_launch(void* const* d_in, const int* in_sizes, int n_in,
                              void* d_out, int out_size, void* d_ws, size_t ws_size,
                              hipStream_t stream) {
    const float* x    = (const float*)d_in[0];
    // d_in[1] = group_mask: unused by the reference
    const float* gxyz = (const float*)d_in[2];

    char* ws = (char*)d_ws;
    _Float16* x1L = (_Float16*)ws;                        // 9,437,184 halves (18.9 MB)
    _Float16* whF = x1L + 9437184;                        // 65,536 halves
    float* lbf = (float*)(whF + 65536);                   // 64
    float* wnP = lbf + 64;                                // 248

    prep_conv0_k<<<1414, 256, 0, stream>>>(
        (const float*)d_in[3],  (const float*)d_in[4],  (const float*)d_in[5],
        (const float*)d_in[6],  (const float*)d_in[7],  (const float*)d_in[8],
        (const float*)d_in[9],  (const float*)d_in[10], (const float*)d_in[11],
        (const float*)d_in[12], (const float*)d_in[13], (const float*)d_in[14],
        (const float*)d_in[15], (const float*)d_in[16], (const float*)d_in[17],
        (const float*)d_in[18], (const float*)d_in[19], (const float*)d_in[20],
        (const float*)d_in[21], (const float*)d_in[22], (const float*)d_in[23],
        (const float*)d_in[24], (const float*)d_in[25], (const float*)d_in[26],
        (const float*)d_in[27], (const float*)d_in[28], (const float*)d_in[29],
        (const float*)d_in[30], (const float*)d_in[31], (const float*)d_in[32],
        x, x1L, whF, lbf, wnP);

    pconv_main_k<<<4 * 96 * 6, 128, 0, stream>>>(gxyz, x1L, whF, lbf, wnP,
                                                 (float*)d_out);
}